// Round 8
// baseline (1091.861 us; speedup 1.0000x reference)
//
#include <hip/hip_runtime.h>
#include <hip/hip_fp16.h>

#define DIMM 128
#define LEAKY_S 0.01f
#define EPS_BN 1e-5f

typedef _Float16 half8 __attribute__((ext_vector_type(8)));
typedef float f32x4 __attribute__((ext_vector_type(4)));

// ---------------------------------------------------------------------------
// Graph preprocessing: degree -> rowptr (3-phase parallel scan) -> CSR fill
// ---------------------------------------------------------------------------

__global__ __launch_bounds__(256) void k_deg(const int* __restrict__ dst, int* __restrict__ deg, int E, int N) {
    int i = blockIdx.x * 256 + threadIdx.x;
    if (i < E) {
        int d = dst[i];
        if ((unsigned)d < (unsigned)N) atomicAdd(&deg[d], 1);
    }
}

__global__ __launch_bounds__(256) void k_dinv(const int* __restrict__ deg, float* __restrict__ dinv, int N) {
    int i = blockIdx.x * 256 + threadIdx.x;
    if (i < N) dinv[i] = rsqrtf((float)(deg[i] + 1));   // +1 self-loop
}

__global__ __launch_bounds__(256) void k_scanA(const int* __restrict__ deg, int* __restrict__ bsum, int n) {
    __shared__ int ws[4];
    int tid = threadIdx.x, lane = tid & 63, wid = tid >> 6;
    int base = blockIdx.x * 1024;
    int s = 0;
    #pragma unroll
    for (int j = 0; j < 4; ++j) {
        int i = base + j * 256 + tid;
        if (i < n) s += deg[i];
    }
    #pragma unroll
    for (int off = 32; off > 0; off >>= 1) s += __shfl_down(s, (unsigned)off, 64);
    if (lane == 0) ws[wid] = s;
    __syncthreads();
    if (tid == 0) bsum[blockIdx.x] = ws[0] + ws[1] + ws[2] + ws[3];
}

__global__ __launch_bounds__(64) void k_scanB(const int* __restrict__ bsum, int* __restrict__ bofs,
                                              int* __restrict__ rowptr, int nb, int n) {
    if (threadIdx.x == 0) {
        int run = 0;
        for (int j = 0; j < nb; ++j) { bofs[j] = run; run += bsum[j]; }
        rowptr[n] = run;
    }
}

__global__ __launch_bounds__(1024) void k_scanC(const int* __restrict__ deg, const int* __restrict__ bofs,
                                                int* __restrict__ rowptr, int n) {
    __shared__ int wsum[16];
    int tid = threadIdx.x, lane = tid & 63, wid = tid >> 6;
    int i = blockIdx.x * 1024 + tid;
    int v = (i < n) ? deg[i] : 0;
    int s = v;
    #pragma unroll
    for (int off = 1; off < 64; off <<= 1) {
        int t = __shfl_up(s, (unsigned)off, 64);
        if (lane >= off) s += t;
    }
    if (lane == 63) wsum[wid] = s;
    __syncthreads();
    if (wid == 0 && lane < 16) {
        int ws = wsum[lane];
        #pragma unroll
        for (int off = 1; off < 16; off <<= 1) {
            int t = __shfl_up(ws, (unsigned)off, 64);
            if (lane >= off) ws += t;
        }
        wsum[lane] = ws;
    }
    __syncthreads();
    int woff = wid ? wsum[wid - 1] : 0;
    if (i < n) rowptr[i] = bofs[blockIdx.x] + woff + (s - v);
}

__global__ __launch_bounds__(256) void k_fill(const int* __restrict__ src, const int* __restrict__ dst,
                                              const int* __restrict__ rowptr, int* __restrict__ cursor,
                                              const float* __restrict__ dinv,
                                              int2* __restrict__ csr, int E, int N) {
    int i = blockIdx.x * 256 + threadIdx.x;
    if (i < E) {
        int d = dst[i], s = src[i];
        if ((unsigned)d < (unsigned)N && (unsigned)s < (unsigned)N) {
            int pos = atomicAdd(&cursor[d], 1);
            int idx = rowptr[d] + pos;
            csr[idx] = make_int2(s, __float_as_int(dinv[s] * dinv[d]));
        }
    }
}

// ---------------------------------------------------------------------------
// W/BN fold: (a*x+b)@W + bias == x@W' + bias', W'[n][k]=f16(a_k W[k][n]),
// bias'[n] = bias_n + sum_k b_k W[k][n]. (a,b) = BN affine of previous layer.
// ---------------------------------------------------------------------------

__global__ __launch_bounds__(128) void k_wbn(const float* __restrict__ W, const float* __restrict__ bias,
                                             const float* __restrict__ stats, const float* __restrict__ gamma,
                                             const float* __restrict__ beta,
                                             __half* __restrict__ Wt, float* __restrict__ bias2,
                                             int ident, float inv_n) {
    __shared__ float red2[2];
    int n = blockIdx.x;
    int k = threadIdx.x;
    float a = 1.f, b = 0.f;
    if (!ident) {
        float mu  = stats[k] * inv_n;
        float var = stats[128 + k] * inv_n - mu * mu;
        a = gamma[k] * rsqrtf(var + EPS_BN);
        b = beta[k] - mu * a;
    }
    float w = W[k * DIMM + n];
    Wt[n * DIMM + k] = __float2half(a * w);
    float p = b * w;
    #pragma unroll
    for (int off = 32; off > 0; off >>= 1) p += __shfl_down(p, (unsigned)off, 64);
    if ((k & 63) == 0) red2[k >> 6] = p;
    __syncthreads();
    if (k == 0) bias2[n] = bias[n] + red2[0] + red2[1];
}

// ---------------------------------------------------------------------------
// MFMA GEMM: out16[N,128] = f16( A @ W' + bias' ). XOR-swizzled LDS.
// ---------------------------------------------------------------------------

__global__ __launch_bounds__(256) void k_gemm(const void* __restrict__ A, const __half* __restrict__ Wt,
                                              const float* __restrict__ bias2,
                                              __half* __restrict__ out, int N, int a_half) {
    __shared__ char smem[128 * 256];
    int tid = threadIdx.x;
    int lane = tid & 63, wid = tid >> 6;
    int quad = lane >> 4, lm = lane & 15;
    int row0 = blockIdx.x * 128;

    const float*  Af = (const float*)A;
    const __half* Ah = (const __half*)A;
    #pragma unroll
    for (int it = 0; it < 8; ++it) {
        int i = it * 256 + tid;
        int r = i >> 4, c = i & 15;           // row 0..127, 16B-chunk 0..15
        int gr = row0 + r;
        union { _Float16 h[8]; uint4 u; } pk;
        if (gr < N) {
            if (a_half) {
                pk.u = *(const uint4*)(Ah + (size_t)gr * DIMM + c * 8);
            } else {
                float4 f0 = *(const float4*)(Af + (size_t)gr * DIMM + c * 8);
                float4 f1 = *(const float4*)(Af + (size_t)gr * DIMM + c * 8 + 4);
                pk.h[0] = (_Float16)f0.x; pk.h[1] = (_Float16)f0.y;
                pk.h[2] = (_Float16)f0.z; pk.h[3] = (_Float16)f0.w;
                pk.h[4] = (_Float16)f1.x; pk.h[5] = (_Float16)f1.y;
                pk.h[6] = (_Float16)f1.z; pk.h[7] = (_Float16)f1.w;
            }
        } else {
            pk.u = make_uint4(0, 0, 0, 0);
        }
        *(uint4*)(smem + r * 256 + ((c ^ (r & 7)) << 4)) = pk.u;
    }

    f32x4 acc[2][8];
    #pragma unroll
    for (int c = 0; c < 8; ++c) {
        float bc = bias2[c * 16 + lm];
        acc[0][c] = (f32x4){bc, bc, bc, bc};
        acc[1][c] = acc[0][c];
    }
    __syncthreads();

    const _Float16* Wt16 = (const _Float16*)Wt;
    #pragma unroll
    for (int kc = 0; kc < 4; ++kc) {
        int sw = ((kc * 4 + quad) ^ (lm & 7)) << 4;
        half8 a0 = *(const half8*)(smem + (wid * 32 + lm) * 256 + sw);
        half8 a1 = *(const half8*)(smem + (wid * 32 + 16 + lm) * 256 + sw);
        #pragma unroll
        for (int c = 0; c < 8; ++c) {
            half8 b = *(const half8*)(Wt16 + (c * 16 + lm) * DIMM + kc * 32 + quad * 8);
            acc[0][c] = __builtin_amdgcn_mfma_f32_16x16x32_f16(a0, b, acc[0][c], 0, 0, 0);
            acc[1][c] = __builtin_amdgcn_mfma_f32_16x16x32_f16(a1, b, acc[1][c], 0, 0, 0);
        }
    }

    __syncthreads();
    #pragma unroll
    for (int r = 0; r < 2; ++r)
        #pragma unroll
        for (int c = 0; c < 8; ++c)
            #pragma unroll
            for (int i = 0; i < 4; ++i) {
                int rit = wid * 32 + r * 16 + quad * 4 + i;
                int col = c * 16 + lm;
                *(_Float16*)(smem + rit * 256 + col * 2) = (_Float16)acc[r][c][i];
            }
    __syncthreads();
    for (int i = tid; i < 128 * 16; i += 256) {
        int r = i >> 4, seg = i & 15;
        int gr = row0 + r;
        if (gr < N)
            ((uint4*)(out + (size_t)gr * DIMM))[seg] = ((const uint4*)(smem + r * 256))[seg];
    }
}

// ---------------------------------------------------------------------------
// Aggregate: depth-2 software pipeline (extends round-6's +14% csr prefetch
// one level deeper to the GATHER DATA):
//   - gd[8]+us: gather rows for node i issued at END of iteration i-1 (their
//     addresses c1 were staged one iteration earlier) -> latency flies across
//     reduce/store + loop-back + meta loads instead of being waited at once.
//     Single buffer (FMAs consume gd before restage -> WAR via in-order issue).
//   - csr depth 2: c0 = weights of node i, c1 = addrs/weights of node i+1,
//     c2 staged for node i+2 each iteration. Metadata (rowptr/dinv) depth 2.
//   - all staging branch-free (clamped idx, zeroed weights) -- round-4 showed
//     per-slot branches destroy load batching. deg>32 tail inline (rare).
//   - self term only in grp==0; fused BN stats. No min-waves bound (round-2:
//     forced VGPR=32 spilled, WRITE 27->670MB). Spill sentinel: WRITE_SIZE.
// ---------------------------------------------------------------------------

__global__ __launch_bounds__(256) void k_agg(const __half* __restrict__ t, __half* __restrict__ out,
                                             const int* __restrict__ rowptr, const int2* __restrict__ csr,
                                             const float* __restrict__ dinv,
                                             float* __restrict__ stats, int N, int nwaves) {
    int tid = threadIdx.x;
    int lane = tid & 63, wid = tid >> 6;
    int grp = lane >> 4;       // edge sub-slot 0..3
    int l16 = lane & 15;       // covers cols [8*l16, 8*l16+8)
    int gw = blockIdx.x * 4 + wid;

    float sx[8] = {0.f, 0.f, 0.f, 0.f, 0.f, 0.f, 0.f, 0.f};
    float qx[8] = {0.f, 0.f, 0.f, 0.f, 0.f, 0.f, 0.f, 0.f};

    union H8 { half8 h; __half2 h2[4]; };

    int node = gw;
    int e0 = 0, e1 = 0;   float di = 0.f;
    int ep0 = 0, ep1 = 0; float dip = 0.f;
    int2 c0[8], c1[8];
    H8 gd[8]; H8 us;
    int nxt = node + nwaves;

    if (node < N) {
        e0 = rowptr[node]; e1 = rowptr[node + 1]; di = dinv[node];
        int last = e1 - 1;
        #pragma unroll
        for (int j = 0; j < 8; ++j) {
            int idx = e0 + 4 * j + grp;
            int idxc = idx < last ? idx : last;
            if (idxc < 0) idxc = 0;              // deg-0 safety
            c0[j] = csr[idxc];
            if (idx >= e1) c0[j].y = 0;
        }
        // issue gathers for the first node
        #pragma unroll
        for (int j = 0; j < 8; ++j)
            gd[j].h = *(const half8*)(t + ((size_t)(unsigned)c0[j].x << 7) + l16 * 8);
        us.h = *(const half8*)(t + ((size_t)(unsigned)node << 7) + l16 * 8);
        // next node's metadata + csr
        if (nxt < N) { ep0 = rowptr[nxt]; ep1 = rowptr[nxt + 1]; dip = dinv[nxt]; }
        int lastn = ep1 - 1;
        #pragma unroll
        for (int j = 0; j < 8; ++j) {
            int idx = ep0 + 4 * j + grp;
            int idxc = idx < lastn ? idx : lastn;
            if (idxc < 0) idxc = 0;
            c1[j] = csr[idxc];
            if (idx >= ep1) c1[j].y = 0;
        }
    }

    while (node < N) {
        // 1. metadata for node i+2 (branchless clamp; arrives by c2 staging)
        int n2 = nxt + nwaves;
        int n2c = n2 < N ? n2 : 0;
        int f0 = rowptr[n2c], f1 = rowptr[n2c + 1];
        float di2 = dinv[n2c];
        if (n2 >= N) { f0 = 0; f1 = 0; di2 = 0.f; }

        // 2. compute current node: gd (issued last iter) x c0 weights
        float v[8] = {0.f, 0.f, 0.f, 0.f, 0.f, 0.f, 0.f, 0.f};
        #pragma unroll
        for (int j = 0; j < 8; ++j) {
            float wgt = __int_as_float(c0[j].y);
            #pragma unroll
            for (int p = 0; p < 4; ++p) {
                float2 f = __half22float2(gd[j].h2[p]);
                v[2 * p]     = fmaf(wgt, f.x, v[2 * p]);
                v[2 * p + 1] = fmaf(wgt, f.y, v[2 * p + 1]);
            }
        }
        // rare extra volleys (deg > 32), direct round-3 style
        for (int e = e0 + 32; e < e1; e += 32) {
            int2 cx[8];
            int last = e1 - 1;
            #pragma unroll
            for (int j = 0; j < 8; ++j) {
                int idx = e + 4 * j + grp;
                int idxc = idx < last ? idx : last;
                cx[j] = csr[idxc];
                if (idx >= e1) cx[j].y = 0;
            }
            #pragma unroll
            for (int j = 0; j < 8; ++j) {
                float wgt = __int_as_float(cx[j].y);
                H8 g;
                g.h = *(const half8*)(t + ((size_t)(unsigned)cx[j].x << 7) + l16 * 8);
                #pragma unroll
                for (int p = 0; p < 4; ++p) {
                    float2 f = __half22float2(g.h2[p]);
                    v[2 * p]     = fmaf(wgt, f.x, v[2 * p]);
                    v[2 * p + 1] = fmaf(wgt, f.y, v[2 * p + 1]);
                }
            }
        }
        // self-loop term — ONLY group 0 (groups summed by the reduction)
        float sn = (grp == 0) ? di * di : 0.f;
        #pragma unroll
        for (int p = 0; p < 4; ++p) {
            float2 f = __half22float2(us.h2[p]);
            v[2 * p]     = fmaf(sn, f.x, v[2 * p]);
            v[2 * p + 1] = fmaf(sn, f.y, v[2 * p + 1]);
        }

        // 3. stage gathers for node i+1 (addresses c1, arrived long ago);
        //    they fly across reduce/store + loop-back + meta loads
        #pragma unroll
        for (int j = 0; j < 8; ++j)
            gd[j].h = *(const half8*)(t + ((size_t)(unsigned)c1[j].x << 7) + l16 * 8);
        {
            int nr = nxt < N ? nxt : 0;
            us.h = *(const half8*)(t + ((size_t)(unsigned)nr << 7) + l16 * 8);
        }

        // 4. stage csr for node i+2
        int2 c2[8];
        {
            int last2 = f1 - 1;
            #pragma unroll
            for (int j = 0; j < 8; ++j) {
                int idx = f0 + 4 * j + grp;
                int idxc = idx < last2 ? idx : last2;
                if (idxc < 0) idxc = 0;
                c2[j] = csr[idxc];
                if (idx >= f1) c2[j].y = 0;
            }
        }

        // 5. reduce / activate / stats / store
        #pragma unroll
        for (int i = 0; i < 8; ++i) {
            v[i] += __shfl_down(v[i], 32, 64);
            v[i] += __shfl_down(v[i], 16, 64);
        }
        if (grp == 0) {
            union { _Float16 h[8]; uint4 u4; } pk;
            #pragma unroll
            for (int i = 0; i < 8; ++i) {
                v[i] = v[i] > 0.f ? v[i] : LEAKY_S * v[i];
                sx[i] += v[i];
                qx[i] += v[i] * v[i];
                pk.h[i] = (_Float16)v[i];
            }
            *(uint4*)(out + ((size_t)(unsigned)node << 7) + l16 * 8) = pk.u4;
        }

        // 6. rotate pipeline state
        #pragma unroll
        for (int j = 0; j < 8; ++j) { c0[j] = c1[j]; c1[j] = c2[j]; }
        node = nxt; e0 = ep0; e1 = ep1; di = dip;
        nxt = n2;  ep0 = f0;  ep1 = f1;  dip = di2;
    }

    __shared__ float red[4 * 128];
    if (grp == 0) {
        *(float4*)(red + wid * 128 + l16 * 8)     = make_float4(sx[0], sx[1], sx[2], sx[3]);
        *(float4*)(red + wid * 128 + l16 * 8 + 4) = make_float4(sx[4], sx[5], sx[6], sx[7]);
    }
    __syncthreads();
    if (tid < 128) {
        float s = red[tid] + red[128 + tid] + red[256 + tid] + red[384 + tid];
        atomicAdd(&stats[tid], s);
    }
    __syncthreads();
    if (grp == 0) {
        *(float4*)(red + wid * 128 + l16 * 8)     = make_float4(qx[0], qx[1], qx[2], qx[3]);
        *(float4*)(red + wid * 128 + l16 * 8 + 4) = make_float4(qx[4], qx[5], qx[6], qx[7]);
    }
    __syncthreads();
    if (tid < 128) {
        float s = red[tid] + red[128 + tid] + red[256 + tid] + red[384 + tid];
        atomicAdd(&stats[128 + tid], s);
    }
}

// ---------------------------------------------------------------------------
// Pooling (h is fp16; pool accum fp32). Final BN affine computed in poolfin.
// ---------------------------------------------------------------------------

__global__ __launch_bounds__(64) void k_cnt_bs(const int* __restrict__ batch, int* __restrict__ cnt, int N, int G) {
    int g = blockIdx.x * 64 + threadIdx.x;
    if (g >= G) return;
    int lo = 0, hi = N;
    while (lo < hi) { int mid = (lo + hi) >> 1; if (batch[mid] < g) lo = mid + 1; else hi = mid; }
    int lb = lo;
    lo = 0; hi = N;
    while (lo < hi) { int mid = (lo + hi) >> 1; if (batch[mid] <= g) lo = mid + 1; else hi = mid; }
    cnt[g] = lo - lb;
}

__global__ __launch_bounds__(128) void k_pool(const __half* __restrict__ h, const int* __restrict__ batch,
                                              float* __restrict__ pool, int N, int G) {
    const int CHUNK = 128;
    int start = blockIdx.x * CHUNK;
    if (start >= N) return;
    int end = min(start + CHUNK, N);
    int tid = threadIdx.x;
    float acc = 0.f;
    int cur = batch[start];
    for (int n = start; n < end; ++n) {
        int g = batch[n];
        if (g != cur) {
            if ((unsigned)cur < (unsigned)G) atomicAdd(&pool[(size_t)cur * DIMM + tid], acc);
            acc = 0.f; cur = g;
        }
        acc += __half2float(h[(size_t)n * DIMM + tid]);
    }
    if ((unsigned)cur < (unsigned)G) atomicAdd(&pool[(size_t)cur * DIMM + tid], acc);
}

__global__ __launch_bounds__(256) void k_poolfin(const float* __restrict__ pool, const int* __restrict__ cnt,
                                                 const float* __restrict__ stats, const float* __restrict__ gamma,
                                                 const float* __restrict__ beta,
                                                 float* __restrict__ out, int G, float inv_n) {
    int idx = blockIdx.x * 256 + threadIdx.x;
    if (idx < G * DIMM) {
        int g = idx >> 7, c = idx & 127;
        float mu  = stats[c] * inv_n;
        float var = stats[128 + c] * inv_n - mu * mu;
        float a = gamma[c] * rsqrtf(var + EPS_BN);
        float b = beta[c] - mu * a;
        float m = pool[idx] / (float)max(cnt[g], 1);
        out[idx] = a * m + b;
    }
}

// ---------------------------------------------------------------------------

extern "C" void kernel_launch(void* const* d_in, const int* in_sizes, int n_in,
                              void* d_out, int out_size, void* d_ws, size_t ws_size,
                              hipStream_t stream) {
    const float* x      = (const float*)d_in[0];
    const int*   ei     = (const int*)d_in[1];
    const int*   batch  = (const int*)d_in[2];
    const float* Ws     = (const float*)d_in[3];
    const float* bs     = (const float*)d_in[4];
    const float* gammas = (const float*)d_in[5];
    const float* betas  = (const float*)d_in[6];
    float* outp = (float*)d_out;

    int N = in_sizes[2];
    int E = in_sizes[1] / 2;
    int L = in_sizes[3] / (DIMM * DIMM);
    int G = out_size / DIMM;

    const int* srcv = ei;
    const int* dstv = ei + E;

    int nb = (N + 1023) / 1024;

    char* w = (char*)d_ws;
    auto alloc = [&](size_t bytes) { char* p = w; w += (bytes + 511) & ~size_t(511); return p; };
    int*    deg    = (int*)   alloc((size_t)N * 4);
    int*    cursor = (int*)   alloc((size_t)N * 4);
    int*    rowptr = (int*)   alloc((size_t)(N + 1) * 4);
    int*    bsum   = (int*)   alloc((size_t)nb * 4);
    int*    bofs   = (int*)   alloc((size_t)nb * 4);
    int2*   csr    = (int2*)  alloc((size_t)E * 8);
    float*  dinv   = (float*) alloc((size_t)N * 4);
    __half* hA     = (__half*)alloc((size_t)N * DIMM * 2);
    __half* hB     = (__half*)alloc((size_t)N * DIMM * 2);
    __half* Wt     = (__half*)alloc((size_t)DIMM * DIMM * 2);   // per-layer, rebuilt by k_wbn
    float*  bias2  = (float*) alloc((size_t)DIMM * 4);
    float*  stats  = (float*) alloc((size_t)L * 256 * 4);
    float*  pool   = (float*) alloc((size_t)G * DIMM * 4);
    int*    cnt    = (int*)   alloc((size_t)G * 4);

    hipMemsetAsync(deg,    0, (size_t)N * 4, stream);
    hipMemsetAsync(cursor, 0, (size_t)N * 4, stream);
    hipMemsetAsync(stats,  0, (size_t)L * 256 * 4, stream);
    hipMemsetAsync(pool,   0, (size_t)G * DIMM * 4, stream);

    float inv_n = 1.0f / (float)N;

    k_deg  <<<(E + 255) / 256, 256, 0, stream>>>(dstv, deg, E, N);
    k_dinv <<<(N + 255) / 256, 256, 0, stream>>>(deg, dinv, N);
    k_scanA<<<nb, 256, 0, stream>>>(deg, bsum, N);
    k_scanB<<<1, 64, 0, stream>>>(bsum, bofs, rowptr, nb, N);
    k_scanC<<<nb, 1024, 0, stream>>>(deg, bofs, rowptr, N);
    k_fill <<<(E + 255) / 256, 256, 0, stream>>>(srcv, dstv, rowptr, cursor, dinv, csr, E, N);

    const void* cur_in = (const void*)x;
    int a_half = 0;
    for (int l = 0; l < L; ++l) {
        // fold BN affine of layer l-1 into W_l / bias_l
        const float* st = (l > 0) ? stats + (size_t)(l - 1) * 256 : stats;
        const float* gm = (l > 0) ? gammas + (size_t)(l - 1) * DIMM : gammas;
        const float* bt = (l > 0) ? betas + (size_t)(l - 1) * DIMM : betas;
        k_wbn<<<DIMM, DIMM, 0, stream>>>(Ws + (size_t)l * DIMM * DIMM, bs + (size_t)l * DIMM,
                                         st, gm, bt, Wt, bias2, (l == 0) ? 1 : 0, inv_n);
        k_gemm<<<(N + 127) / 128, 256, 0, stream>>>(cur_in, Wt, bias2, hA, N, a_half);
        const int nblk = 2048;   // 8192 waves, strided node assignment
        k_agg<<<nblk, 256, 0, stream>>>(hA, hB, rowptr, csr, dinv,
                                        stats + (size_t)l * 256, N, nblk * 4);
        cur_in = (const void*)hB;
        a_half = 1;
    }

    k_cnt_bs<<<(G + 63) / 64, 64, 0, stream>>>(batch, cnt, N, G);
    k_pool<<<(N + 127) / 128, 128, 0, stream>>>(hB, batch, pool, N, G);
    k_poolfin<<<(G * DIMM + 255) / 256, 256, 0, stream>>>(pool, cnt, stats + (size_t)(L - 1) * 256,
                                                          gammas + (size_t)(L - 1) * DIMM,
                                                          betas + (size_t)(L - 1) * DIMM, outp, G, inv_n);
}

// Round 9
// 1074.086 us; speedup vs baseline: 1.0165x; 1.0165x over previous
//
#include <hip/hip_runtime.h>
#include <hip/hip_fp16.h>

#define DIMM 128
#define LEAKY_S 0.01f
#define EPS_BN 1e-5f

typedef _Float16 half8 __attribute__((ext_vector_type(8)));
typedef float f32x4 __attribute__((ext_vector_type(4)));

// ---------------------------------------------------------------------------
// Graph preprocessing: degree -> rowptr (3-phase parallel scan) -> CSR fill
// ---------------------------------------------------------------------------

__global__ __launch_bounds__(256) void k_deg(const int* __restrict__ dst, int* __restrict__ deg, int E, int N) {
    int i = blockIdx.x * 256 + threadIdx.x;
    if (i < E) {
        int d = dst[i];
        if ((unsigned)d < (unsigned)N) atomicAdd(&deg[d], 1);
    }
}

// scanA also produces dinv (fused former k_dinv): both only need final deg.
__global__ __launch_bounds__(256) void k_scanA(const int* __restrict__ deg, int* __restrict__ bsum,
                                               float* __restrict__ dinv, int n) {
    __shared__ int ws[4];
    int tid = threadIdx.x, lane = tid & 63, wid = tid >> 6;
    int base = blockIdx.x * 1024;
    int s = 0;
    #pragma unroll
    for (int j = 0; j < 4; ++j) {
        int i = base + j * 256 + tid;
        if (i < n) {
            int d = deg[i];
            s += d;
            dinv[i] = rsqrtf((float)(d + 1));   // +1 self-loop
        }
    }
    #pragma unroll
    for (int off = 32; off > 0; off >>= 1) s += __shfl_down(s, (unsigned)off, 64);
    if (lane == 0) ws[wid] = s;
    __syncthreads();
    if (tid == 0) bsum[blockIdx.x] = ws[0] + ws[1] + ws[2] + ws[3];
}

__global__ __launch_bounds__(64) void k_scanB(const int* __restrict__ bsum, int* __restrict__ bofs,
                                              int* __restrict__ rowptr, int nb, int n) {
    if (threadIdx.x == 0) {
        int run = 0;
        for (int j = 0; j < nb; ++j) { bofs[j] = run; run += bsum[j]; }
        rowptr[n] = run;
    }
}

__global__ __launch_bounds__(1024) void k_scanC(const int* __restrict__ deg, const int* __restrict__ bofs,
                                                int* __restrict__ rowptr, int n) {
    __shared__ int wsum[16];
    int tid = threadIdx.x, lane = tid & 63, wid = tid >> 6;
    int i = blockIdx.x * 1024 + tid;
    int v = (i < n) ? deg[i] : 0;
    int s = v;
    #pragma unroll
    for (int off = 1; off < 64; off <<= 1) {
        int t = __shfl_up(s, (unsigned)off, 64);
        if (lane >= off) s += t;
    }
    if (lane == 63) wsum[wid] = s;
    __syncthreads();
    if (wid == 0 && lane < 16) {
        int ws = wsum[lane];
        #pragma unroll
        for (int off = 1; off < 16; off <<= 1) {
            int t = __shfl_up(ws, (unsigned)off, 64);
            if (lane >= off) ws += t;
        }
        wsum[lane] = ws;
    }
    __syncthreads();
    int woff = wid ? wsum[wid - 1] : 0;
    if (i < n) rowptr[i] = bofs[blockIdx.x] + woff + (s - v);
}

__global__ __launch_bounds__(256) void k_fill(const int* __restrict__ src, const int* __restrict__ dst,
                                              const int* __restrict__ rowptr, int* __restrict__ cursor,
                                              const float* __restrict__ dinv,
                                              int2* __restrict__ csr, int E, int N) {
    int i = blockIdx.x * 256 + threadIdx.x;
    if (i < E) {
        int d = dst[i], s = src[i];
        if ((unsigned)d < (unsigned)N && (unsigned)s < (unsigned)N) {
            int pos = atomicAdd(&cursor[d], 1);
            int idx = rowptr[d] + pos;
            csr[idx] = make_int2(s, __float_as_int(dinv[s] * dinv[d]));
        }
    }
}

// ---------------------------------------------------------------------------
// W/BN fold: (a*x+b)@W + bias == x@W' + bias', W'[n][k]=f16(a_k W[k][n]),
// bias'[n] = bias_n + sum_k b_k W[k][n]. (a,b) = BN affine of previous layer.
// ---------------------------------------------------------------------------

__global__ __launch_bounds__(128) void k_wbn(const float* __restrict__ W, const float* __restrict__ bias,
                                             const float* __restrict__ stats, const float* __restrict__ gamma,
                                             const float* __restrict__ beta,
                                             __half* __restrict__ Wt, float* __restrict__ bias2,
                                             int ident, float inv_n) {
    __shared__ float red2[2];
    int n = blockIdx.x;
    int k = threadIdx.x;
    float a = 1.f, b = 0.f;
    if (!ident) {
        float mu  = stats[k] * inv_n;
        float var = stats[128 + k] * inv_n - mu * mu;
        a = gamma[k] * rsqrtf(var + EPS_BN);
        b = beta[k] - mu * a;
    }
    float w = W[k * DIMM + n];
    Wt[n * DIMM + k] = __float2half(a * w);
    float p = b * w;
    #pragma unroll
    for (int off = 32; off > 0; off >>= 1) p += __shfl_down(p, (unsigned)off, 64);
    if ((k & 63) == 0) red2[k >> 6] = p;
    __syncthreads();
    if (k == 0) bias2[n] = bias[n] + red2[0] + red2[1];
}

// ---------------------------------------------------------------------------
// MFMA GEMM: out16[N,128] = f16( A @ W' + bias' ). XOR-swizzled LDS.
// ---------------------------------------------------------------------------

__global__ __launch_bounds__(256) void k_gemm(const void* __restrict__ A, const __half* __restrict__ Wt,
                                              const float* __restrict__ bias2,
                                              __half* __restrict__ out, int N, int a_half) {
    __shared__ char smem[128 * 256];
    int tid = threadIdx.x;
    int lane = tid & 63, wid = tid >> 6;
    int quad = lane >> 4, lm = lane & 15;
    int row0 = blockIdx.x * 128;

    const float*  Af = (const float*)A;
    const __half* Ah = (const __half*)A;
    #pragma unroll
    for (int it = 0; it < 8; ++it) {
        int i = it * 256 + tid;
        int r = i >> 4, c = i & 15;           // row 0..127, 16B-chunk 0..15
        int gr = row0 + r;
        union { _Float16 h[8]; uint4 u; } pk;
        if (gr < N) {
            if (a_half) {
                pk.u = *(const uint4*)(Ah + (size_t)gr * DIMM + c * 8);
            } else {
                float4 f0 = *(const float4*)(Af + (size_t)gr * DIMM + c * 8);
                float4 f1 = *(const float4*)(Af + (size_t)gr * DIMM + c * 8 + 4);
                pk.h[0] = (_Float16)f0.x; pk.h[1] = (_Float16)f0.y;
                pk.h[2] = (_Float16)f0.z; pk.h[3] = (_Float16)f0.w;
                pk.h[4] = (_Float16)f1.x; pk.h[5] = (_Float16)f1.y;
                pk.h[6] = (_Float16)f1.z; pk.h[7] = (_Float16)f1.w;
            }
        } else {
            pk.u = make_uint4(0, 0, 0, 0);
        }
        *(uint4*)(smem + r * 256 + ((c ^ (r & 7)) << 4)) = pk.u;
    }

    f32x4 acc[2][8];
    #pragma unroll
    for (int c = 0; c < 8; ++c) {
        float bc = bias2[c * 16 + lm];
        acc[0][c] = (f32x4){bc, bc, bc, bc};
        acc[1][c] = acc[0][c];
    }
    __syncthreads();

    const _Float16* Wt16 = (const _Float16*)Wt;
    #pragma unroll
    for (int kc = 0; kc < 4; ++kc) {
        int sw = ((kc * 4 + quad) ^ (lm & 7)) << 4;
        half8 a0 = *(const half8*)(smem + (wid * 32 + lm) * 256 + sw);
        half8 a1 = *(const half8*)(smem + (wid * 32 + 16 + lm) * 256 + sw);
        #pragma unroll
        for (int c = 0; c < 8; ++c) {
            half8 b = *(const half8*)(Wt16 + (c * 16 + lm) * DIMM + kc * 32 + quad * 8);
            acc[0][c] = __builtin_amdgcn_mfma_f32_16x16x32_f16(a0, b, acc[0][c], 0, 0, 0);
            acc[1][c] = __builtin_amdgcn_mfma_f32_16x16x32_f16(a1, b, acc[1][c], 0, 0, 0);
        }
    }

    __syncthreads();
    #pragma unroll
    for (int r = 0; r < 2; ++r)
        #pragma unroll
        for (int c = 0; c < 8; ++c)
            #pragma unroll
            for (int i = 0; i < 4; ++i) {
                int rit = wid * 32 + r * 16 + quad * 4 + i;
                int col = c * 16 + lm;
                *(_Float16*)(smem + rit * 256 + col * 2) = (_Float16)acc[r][c][i];
            }
    __syncthreads();
    for (int i = tid; i < 128 * 16; i += 256) {
        int r = i >> 4, seg = i & 15;
        int gr = row0 + r;
        if (gr < N)
            ((uint4*)(out + (size_t)gr * DIMM))[seg] = ((const uint4*)(smem + r * 256))[seg];
    }
}

// ---------------------------------------------------------------------------
// Aggregate: EXACT round-6 structure (measured 88.6 us, best of 5 variants):
// branch-free 32-edge volleys (clamp+zero-weight), metadata prefetch, hoisted
// self row, cross-node csr prefetch into separate cn[8], self term only in
// grp==0, fused BN stats. VGPR 64 (at the occupancy step boundary).
// Rejected by measurement: per-slot guards (r4, +25%), forced min-waves
// (r2, spill 27->670MB), depth-2 gather pipeline (r8, +7% from rotation VALU).
// ---------------------------------------------------------------------------

__global__ __launch_bounds__(256) void k_agg(const __half* __restrict__ t, __half* __restrict__ out,
                                             const int* __restrict__ rowptr, const int2* __restrict__ csr,
                                             const float* __restrict__ dinv,
                                             float* __restrict__ stats, int N, int nwaves) {
    int tid = threadIdx.x;
    int lane = tid & 63, wid = tid >> 6;
    int grp = lane >> 4;       // edge sub-slot 0..3
    int l16 = lane & 15;       // covers cols [8*l16, 8*l16+8)
    int gw = blockIdx.x * 4 + wid;

    float sx[8] = {0.f, 0.f, 0.f, 0.f, 0.f, 0.f, 0.f, 0.f};
    float qx[8] = {0.f, 0.f, 0.f, 0.f, 0.f, 0.f, 0.f, 0.f};

    int node = gw;
    int e0 = 0, e1 = 0;
    float di = 0.f;
    int2 c[8];
    if (node < N) {
        e0 = rowptr[node]; e1 = rowptr[node + 1]; di = dinv[node];
        int last = e1 - 1;
        #pragma unroll
        for (int j = 0; j < 8; ++j) {
            int idx = e0 + 4 * j + grp;
            int idxc = idx < last ? idx : last;
            if (idxc < 0) idxc = 0;              // deg-0 safety
            c[j] = csr[idxc];
            if (idx >= e1) c[j].y = 0;
        }
    }

    while (node < N) {
        // prefetch next node's metadata
        int nxt = node + nwaves;
        int ep0 = 0, ep1 = 0;
        float dip = 0.f;
        if (nxt < N) { ep0 = rowptr[nxt]; ep1 = rowptr[nxt + 1]; dip = dinv[nxt]; }

        // self row: issue now, consume after the edge loop
        union { half8 h; __half2 h2[4]; } us;
        us.h = *(const half8*)(t + ((size_t)(unsigned)node << 7) + l16 * 8);

        float v[8] = {0.f, 0.f, 0.f, 0.f, 0.f, 0.f, 0.f, 0.f};

        // main volley: addresses/weights already staged in c[]
        #pragma unroll
        for (int j = 0; j < 8; ++j) {
            float wgt = __int_as_float(c[j].y);
            union { half8 h; __half2 h2[4]; } g;
            g.h = *(const half8*)(t + ((size_t)(unsigned)c[j].x << 7) + l16 * 8);
            #pragma unroll
            for (int p = 0; p < 4; ++p) {
                float2 f = __half22float2(g.h2[p]);
                v[2 * p]     = fmaf(wgt, f.x, v[2 * p]);
                v[2 * p + 1] = fmaf(wgt, f.y, v[2 * p + 1]);
            }
        }

        // stage NEXT node's first volley into cn (independent -> compiler may
        // hoist these loads under the gather wait; branch-free)
        int2 cn[8];
        {
            int lastn = ep1 - 1;
            #pragma unroll
            for (int j = 0; j < 8; ++j) {
                int idx = ep0 + 4 * j + grp;
                int idxc = idx < lastn ? idx : lastn;
                if (idxc < 0) idxc = 0;          // deg-0 / past-end safety
                cn[j] = csr[idxc];
                if (idx >= ep1) cn[j].y = 0;
            }
        }

        // rare extra volleys (deg > 32), inline staged (round-3 style)
        for (int e = e0 + 32; e < e1; e += 32) {
            int2 cx[8];
            int last = e1 - 1;
            #pragma unroll
            for (int j = 0; j < 8; ++j) {
                int idx = e + 4 * j + grp;
                int idxc = idx < last ? idx : last;
                cx[j] = csr[idxc];
                if (idx >= e1) cx[j].y = 0;
            }
            #pragma unroll
            for (int j = 0; j < 8; ++j) {
                float wgt = __int_as_float(cx[j].y);
                union { half8 h; __half2 h2[4]; } g;
                g.h = *(const half8*)(t + ((size_t)(unsigned)cx[j].x << 7) + l16 * 8);
                #pragma unroll
                for (int p = 0; p < 4; ++p) {
                    float2 f = __half22float2(g.h2[p]);
                    v[2 * p]     = fmaf(wgt, f.x, v[2 * p]);
                    v[2 * p + 1] = fmaf(wgt, f.y, v[2 * p + 1]);
                }
            }
        }

        // self-loop term — ONLY group 0 (groups are summed by the reduction)
        float sn = (grp == 0) ? di * di : 0.f;
        #pragma unroll
        for (int p = 0; p < 4; ++p) {
            float2 f = __half22float2(us.h2[p]);
            v[2 * p]     = fmaf(sn, f.x, v[2 * p]);
            v[2 * p + 1] = fmaf(sn, f.y, v[2 * p + 1]);
        }

        // combine the 4 group partials
        #pragma unroll
        for (int i = 0; i < 8; ++i) {
            v[i] += __shfl_down(v[i], 32, 64);
            v[i] += __shfl_down(v[i], 16, 64);
        }
        if (grp == 0) {
            union { _Float16 h[8]; uint4 u4; } pk;
            #pragma unroll
            for (int i = 0; i < 8; ++i) {
                v[i] = v[i] > 0.f ? v[i] : LEAKY_S * v[i];
                sx[i] += v[i];
                qx[i] += v[i] * v[i];
                pk.h[i] = (_Float16)v[i];
            }
            *(uint4*)(out + ((size_t)(unsigned)node << 7) + l16 * 8) = pk.u4;
        }

        #pragma unroll
        for (int j = 0; j < 8; ++j) c[j] = cn[j];
        node = nxt; e0 = ep0; e1 = ep1; di = dip;
    }

    __shared__ float red[4 * 128];
    if (grp == 0) {
        *(float4*)(red + wid * 128 + l16 * 8)     = make_float4(sx[0], sx[1], sx[2], sx[3]);
        *(float4*)(red + wid * 128 + l16 * 8 + 4) = make_float4(sx[4], sx[5], sx[6], sx[7]);
    }
    __syncthreads();
    if (tid < 128) {
        float s = red[tid] + red[128 + tid] + red[256 + tid] + red[384 + tid];
        atomicAdd(&stats[tid], s);
    }
    __syncthreads();
    if (grp == 0) {
        *(float4*)(red + wid * 128 + l16 * 8)     = make_float4(qx[0], qx[1], qx[2], qx[3]);
        *(float4*)(red + wid * 128 + l16 * 8 + 4) = make_float4(qx[4], qx[5], qx[6], qx[7]);
    }
    __syncthreads();
    if (tid < 128) {
        float s = red[tid] + red[128 + tid] + red[256 + tid] + red[384 + tid];
        atomicAdd(&stats[128 + tid], s);
    }
}

// ---------------------------------------------------------------------------
// Pooling (h fp16, pool accum fp32). poolfin self-computes graph counts
// (fused former k_cnt_bs) + applies the final BN affine.
// ---------------------------------------------------------------------------

__global__ __launch_bounds__(128) void k_pool(const __half* __restrict__ h, const int* __restrict__ batch,
                                              float* __restrict__ pool, int N, int G) {
    const int CHUNK = 128;
    int start = blockIdx.x * CHUNK;
    if (start >= N) return;
    int end = min(start + CHUNK, N);
    int tid = threadIdx.x;
    float acc = 0.f;
    int cur = batch[start];
    for (int n = start; n < end; ++n) {
        int g = batch[n];
        if (g != cur) {
            if ((unsigned)cur < (unsigned)G) atomicAdd(&pool[(size_t)cur * DIMM + tid], acc);
            acc = 0.f; cur = g;
        }
        acc += __half2float(h[(size_t)n * DIMM + tid]);
    }
    if ((unsigned)cur < (unsigned)G) atomicAdd(&pool[(size_t)cur * DIMM + tid], acc);
}

__global__ __launch_bounds__(256) void k_poolfin(const float* __restrict__ pool, const int* __restrict__ batch,
                                                 const float* __restrict__ stats, const float* __restrict__ gamma,
                                                 const float* __restrict__ beta,
                                                 float* __restrict__ out, int N, int G, float inv_n) {
    int idx = blockIdx.x * 256 + threadIdx.x;
    if (idx < G * DIMM) {
        int g = idx >> 7, c = idx & 127;
        // count nodes of graph g by binary search (batch is sorted)
        int lo = 0, hi = N;
        while (lo < hi) { int mid = (lo + hi) >> 1; if (batch[mid] < g) lo = mid + 1; else hi = mid; }
        int lb = lo;
        lo = 0; hi = N;
        while (lo < hi) { int mid = (lo + hi) >> 1; if (batch[mid] <= g) lo = mid + 1; else hi = mid; }
        int cnt = lo - lb;
        float mu  = stats[c] * inv_n;
        float var = stats[128 + c] * inv_n - mu * mu;
        float a = gamma[c] * rsqrtf(var + EPS_BN);
        float b = beta[c] - mu * a;
        float m = pool[idx] / (float)max(cnt, 1);
        out[idx] = a * m + b;
    }
}

// ---------------------------------------------------------------------------

extern "C" void kernel_launch(void* const* d_in, const int* in_sizes, int n_in,
                              void* d_out, int out_size, void* d_ws, size_t ws_size,
                              hipStream_t stream) {
    const float* x      = (const float*)d_in[0];
    const int*   ei     = (const int*)d_in[1];
    const int*   batch  = (const int*)d_in[2];
    const float* Ws     = (const float*)d_in[3];
    const float* bs     = (const float*)d_in[4];
    const float* gammas = (const float*)d_in[5];
    const float* betas  = (const float*)d_in[6];
    float* outp = (float*)d_out;

    int N = in_sizes[2];
    int E = in_sizes[1] / 2;
    int L = in_sizes[3] / (DIMM * DIMM);
    int G = out_size / DIMM;

    const int* srcv = ei;
    const int* dstv = ei + E;

    int nb = (N + 1023) / 1024;

    char* w = (char*)d_ws;
    auto alloc = [&](size_t bytes) { char* p = w; w += (bytes + 511) & ~size_t(511); return p; };
    size_t pN = ((size_t)N * 4 + 511) & ~size_t(511);
    int*    deg    = (int*)   alloc((size_t)N * 4);
    int*    cursor = (int*)   alloc((size_t)N * 4);   // adjacent to deg: one memset covers both
    int*    rowptr = (int*)   alloc((size_t)(N + 1) * 4);
    int*    bsum   = (int*)   alloc((size_t)nb * 4);
    int*    bofs   = (int*)   alloc((size_t)nb * 4);
    int2*   csr    = (int2*)  alloc((size_t)E * 8);
    float*  dinv   = (float*) alloc((size_t)N * 4);
    __half* hA     = (__half*)alloc((size_t)N * DIMM * 2);
    __half* hB     = (__half*)alloc((size_t)N * DIMM * 2);
    __half* Wt     = (__half*)alloc((size_t)DIMM * DIMM * 2);   // per-layer, rebuilt by k_wbn
    float*  bias2  = (float*) alloc((size_t)DIMM * 4);
    float*  stats  = (float*) alloc((size_t)L * 256 * 4);
    float*  pool   = (float*) alloc((size_t)G * DIMM * 4);

    hipMemsetAsync(deg,   0, pN * 2, stream);                    // deg + cursor
    hipMemsetAsync(stats, 0, (size_t)L * 256 * 4, stream);
    hipMemsetAsync(pool,  0, (size_t)G * DIMM * 4, stream);

    float inv_n = 1.0f / (float)N;

    k_deg  <<<(E + 255) / 256, 256, 0, stream>>>(dstv, deg, E, N);
    k_scanA<<<nb, 256, 0, stream>>>(deg, bsum, dinv, N);         // + dinv (fused)
    k_scanB<<<1, 64, 0, stream>>>(bsum, bofs, rowptr, nb, N);
    k_scanC<<<nb, 1024, 0, stream>>>(deg, bofs, rowptr, N);
    k_fill <<<(E + 255) / 256, 256, 0, stream>>>(srcv, dstv, rowptr, cursor, dinv, csr, E, N);

    const void* cur_in = (const void*)x;
    int a_half = 0;
    for (int l = 0; l < L; ++l) {
        // fold BN affine of layer l-1 into W_l / bias_l
        const float* st = (l > 0) ? stats + (size_t)(l - 1) * 256 : stats;
        const float* gm = (l > 0) ? gammas + (size_t)(l - 1) * DIMM : gammas;
        const float* bt = (l > 0) ? betas + (size_t)(l - 1) * DIMM : betas;
        k_wbn<<<DIMM, DIMM, 0, stream>>>(Ws + (size_t)l * DIMM * DIMM, bs + (size_t)l * DIMM,
                                         st, gm, bt, Wt, bias2, (l == 0) ? 1 : 0, inv_n);
        k_gemm<<<(N + 127) / 128, 256, 0, stream>>>(cur_in, Wt, bias2, hA, N, a_half);
        const int nblk = 2048;   // 8192 waves, strided node assignment
        k_agg<<<nblk, 256, 0, stream>>>(hA, hB, rowptr, csr, dinv,
                                        stats + (size_t)l * 256, N, nblk * 4);
        cur_in = (const void*)hB;
        a_half = 1;
    }

    k_pool<<<(N + 127) / 128, 128, 0, stream>>>(hB, batch, pool, N, G);
    k_poolfin<<<(G * DIMM + 255) / 256, 256, 0, stream>>>(pool, batch, stats + (size_t)(L - 1) * 256,
                                                          gammas + (size_t)(L - 1) * DIMM,
                                                          betas + (size_t)(L - 1) * DIMM, outp, N, G, inv_n);
}

// Round 18
// 1061.831 us; speedup vs baseline: 1.0283x; 1.0115x over previous
//
#include <hip/hip_runtime.h>
#include <hip/hip_fp16.h>

#define DIMM 128
#define LEAKY_S 0.01f
#define EPS_BN 1e-5f

typedef _Float16 half8 __attribute__((ext_vector_type(8)));
typedef float f32x4 __attribute__((ext_vector_type(4)));

// global -> LDS direct copy, 16B per lane (wave-uniform LDS base + lane*16)
#define GLDS16(gp, lp)                                                          \
    __builtin_amdgcn_global_load_lds(                                           \
        (const __attribute__((address_space(1))) void*)(gp),                    \
        (__attribute__((address_space(3))) void*)(lp), 16, 0, 0)

// ---------------------------------------------------------------------------
// Graph preprocessing: degree -> rowptr (3-phase parallel scan) -> CSR fill
// ---------------------------------------------------------------------------

__global__ __launch_bounds__(256) void k_deg(const int* __restrict__ dst, int* __restrict__ deg, int E, int N) {
    int i = blockIdx.x * 256 + threadIdx.x;
    if (i < E) {
        int d = dst[i];
        if ((unsigned)d < (unsigned)N) atomicAdd(&deg[d], 1);
    }
}

// scanA also produces dinv (fused former k_dinv): both only need final deg.
__global__ __launch_bounds__(256) void k_scanA(const int* __restrict__ deg, int* __restrict__ bsum,
                                               float* __restrict__ dinv, int n) {
    __shared__ int ws[4];
    int tid = threadIdx.x, lane = tid & 63, wid = tid >> 6;
    int base = blockIdx.x * 1024;
    int s = 0;
    #pragma unroll
    for (int j = 0; j < 4; ++j) {
        int i = base + j * 256 + tid;
        if (i < n) {
            int d = deg[i];
            s += d;
            dinv[i] = rsqrtf((float)(d + 1));   // +1 self-loop
        }
    }
    #pragma unroll
    for (int off = 32; off > 0; off >>= 1) s += __shfl_down(s, (unsigned)off, 64);
    if (lane == 0) ws[wid] = s;
    __syncthreads();
    if (tid == 0) bsum[blockIdx.x] = ws[0] + ws[1] + ws[2] + ws[3];
}

__global__ __launch_bounds__(64) void k_scanB(const int* __restrict__ bsum, int* __restrict__ bofs,
                                              int* __restrict__ rowptr, int nb, int n) {
    if (threadIdx.x == 0) {
        int run = 0;
        for (int j = 0; j < nb; ++j) { bofs[j] = run; run += bsum[j]; }
        rowptr[n] = run;
    }
}

__global__ __launch_bounds__(1024) void k_scanC(const int* __restrict__ deg, const int* __restrict__ bofs,
                                                int* __restrict__ rowptr, int n) {
    __shared__ int wsum[16];
    int tid = threadIdx.x, lane = tid & 63, wid = tid >> 6;
    int i = blockIdx.x * 1024 + tid;
    int v = (i < n) ? deg[i] : 0;
    int s = v;
    #pragma unroll
    for (int off = 1; off < 64; off <<= 1) {
        int t = __shfl_up(s, (unsigned)off, 64);
        if (lane >= off) s += t;
    }
    if (lane == 63) wsum[wid] = s;
    __syncthreads();
    if (wid == 0 && lane < 16) {
        int ws = wsum[lane];
        #pragma unroll
        for (int off = 1; off < 16; off <<= 1) {
            int t = __shfl_up(ws, (unsigned)off, 64);
            if (lane >= off) ws += t;
        }
        wsum[lane] = ws;
    }
    __syncthreads();
    int woff = wid ? wsum[wid - 1] : 0;
    if (i < n) rowptr[i] = bofs[blockIdx.x] + woff + (s - v);
}

__global__ __launch_bounds__(256) void k_fill(const int* __restrict__ src, const int* __restrict__ dst,
                                              const int* __restrict__ rowptr, int* __restrict__ cursor,
                                              const float* __restrict__ dinv,
                                              int2* __restrict__ csr, int E, int N) {
    int i = blockIdx.x * 256 + threadIdx.x;
    if (i < E) {
        int d = dst[i], s = src[i];
        if ((unsigned)d < (unsigned)N && (unsigned)s < (unsigned)N) {
            int pos = atomicAdd(&cursor[d], 1);
            int idx = rowptr[d] + pos;
            csr[idx] = make_int2(s, __float_as_int(dinv[s] * dinv[d]));
        }
    }
}

// ---------------------------------------------------------------------------
// W/BN fold: (a*x+b)@W + bias == x@W' + bias', W'[n][k]=f16(a_k W[k][n]),
// bias'[n] = bias_n + sum_k b_k W[k][n]. (a,b) = BN affine of previous layer.
// ---------------------------------------------------------------------------

__global__ __launch_bounds__(128) void k_wbn(const float* __restrict__ W, const float* __restrict__ bias,
                                             const float* __restrict__ stats, const float* __restrict__ gamma,
                                             const float* __restrict__ beta,
                                             __half* __restrict__ Wt, float* __restrict__ bias2,
                                             int ident, float inv_n) {
    __shared__ float red2[2];
    int n = blockIdx.x;
    int k = threadIdx.x;
    float a = 1.f, b = 0.f;
    if (!ident) {
        float mu  = stats[k] * inv_n;
        float var = stats[128 + k] * inv_n - mu * mu;
        a = gamma[k] * rsqrtf(var + EPS_BN);
        b = beta[k] - mu * a;
    }
    float w = W[k * DIMM + n];
    Wt[n * DIMM + k] = __float2half(a * w);
    float p = b * w;
    #pragma unroll
    for (int off = 32; off > 0; off >>= 1) p += __shfl_down(p, (unsigned)off, 64);
    if ((k & 63) == 0) red2[k >> 6] = p;
    __syncthreads();
    if (k == 0) bias2[n] = bias[n] + red2[0] + red2[1];
}

// ---------------------------------------------------------------------------
// MFMA GEMM: out16[N,128] = f16( A @ W' + bias' ).
// Layers >=1 (fp16 input): A-tile staged via global_load_lds (direct-to-LDS
// DMA, no VGPR round-trip — Common-mistake #1). LDS dest is LINEAR; the XOR
// swizzle is applied to the GLOBAL source chunk (c ^ (r&7), bijective inside
// each 256B row -> coalescing preserved; m173 both-sides rule: pre-swizzled
// source + swizzled ds_read). Rows >= N clamp to row 0: MFMA rows are
// independent and those outputs are store-masked.
// Layer 0 (fp32 input, needs cvt): old VGPR-roundtrip path.
// ---------------------------------------------------------------------------

__global__ __launch_bounds__(256) void k_gemm(const void* __restrict__ A, const __half* __restrict__ Wt,
                                              const float* __restrict__ bias2,
                                              __half* __restrict__ out, int N, int a_half) {
    __shared__ char smem[128 * 256];
    int tid = threadIdx.x;
    int lane = tid & 63, wid = tid >> 6;
    int quad = lane >> 4, lm = lane & 15;
    int row0 = blockIdx.x * 128;

    const float*  Af = (const float*)A;
    const __half* Ah = (const __half*)A;
    if (a_half) {
        #pragma unroll
        for (int it = 0; it < 8; ++it) {
            int i = it * 256 + tid;
            int r = i >> 4, c = i & 15;       // LDS row 0..127, 16B-chunk 0..15
            int gr = row0 + r;
            if (gr >= N) gr = 0;              // clamp: rows independent, masked at store
            int sc = c ^ (r & 7);             // pre-swizzled source chunk
            GLDS16(Ah + (size_t)gr * DIMM + sc * 8, smem + (size_t)i * 16);
        }
    } else {
        #pragma unroll
        for (int it = 0; it < 8; ++it) {
            int i = it * 256 + tid;
            int r = i >> 4, c = i & 15;
            int gr = row0 + r;
            union { _Float16 h[8]; uint4 u; } pk;
            if (gr < N) {
                float4 f0 = *(const float4*)(Af + (size_t)gr * DIMM + c * 8);
                float4 f1 = *(const float4*)(Af + (size_t)gr * DIMM + c * 8 + 4);
                pk.h[0] = (_Float16)f0.x; pk.h[1] = (_Float16)f0.y;
                pk.h[2] = (_Float16)f0.z; pk.h[3] = (_Float16)f0.w;
                pk.h[4] = (_Float16)f1.x; pk.h[5] = (_Float16)f1.y;
                pk.h[6] = (_Float16)f1.z; pk.h[7] = (_Float16)f1.w;
            } else {
                pk.u = make_uint4(0, 0, 0, 0);
            }
            *(uint4*)(smem + r * 256 + ((c ^ (r & 7)) << 4)) = pk.u;
        }
    }

    f32x4 acc[2][8];
    #pragma unroll
    for (int c = 0; c < 8; ++c) {
        float bc = bias2[c * 16 + lm];
        acc[0][c] = (f32x4){bc, bc, bc, bc};
        acc[1][c] = acc[0][c];
    }
    __syncthreads();

    const _Float16* Wt16 = (const _Float16*)Wt;
    #pragma unroll
    for (int kc = 0; kc < 4; ++kc) {
        int sw = ((kc * 4 + quad) ^ (lm & 7)) << 4;
        half8 a0 = *(const half8*)(smem + (wid * 32 + lm) * 256 + sw);
        half8 a1 = *(const half8*)(smem + (wid * 32 + 16 + lm) * 256 + sw);
        #pragma unroll
        for (int c = 0; c < 8; ++c) {
            half8 b = *(const half8*)(Wt16 + (c * 16 + lm) * DIMM + kc * 32 + quad * 8);
            acc[0][c] = __builtin_amdgcn_mfma_f32_16x16x32_f16(a0, b, acc[0][c], 0, 0, 0);
            acc[1][c] = __builtin_amdgcn_mfma_f32_16x16x32_f16(a1, b, acc[1][c], 0, 0, 0);
        }
    }

    __syncthreads();
    #pragma unroll
    for (int r = 0; r < 2; ++r)
        #pragma unroll
        for (int c = 0; c < 8; ++c)
            #pragma unroll
            for (int i = 0; i < 4; ++i) {
                int rit = wid * 32 + r * 16 + quad * 4 + i;
                int col = c * 16 + lm;
                *(_Float16*)(smem + rit * 256 + col * 2) = (_Float16)acc[r][c][i];
            }
    __syncthreads();
    for (int i = tid; i < 128 * 16; i += 256) {
        int r = i >> 4, seg = i & 15;
        int gr = row0 + r;
        if (gr < N)
            ((uint4*)(out + (size_t)gr * DIMM))[seg] = ((const uint4*)(smem + r * 256))[seg];
    }
}

// ---------------------------------------------------------------------------
// Aggregate: EXACT round-6 structure (measured 88.6-90.4 us, best of 5):
// branch-free 32-edge volleys (clamp+zero-weight), metadata prefetch, hoisted
// self row, cross-node csr prefetch into separate cn[8], self term only in
// grp==0, fused BN stats. VGPR 64 (at the occupancy step boundary).
// Rejected by measurement: per-slot guards (r4, +25%), forced min-waves
// (r2, spill 27->670MB), depth-2 gather pipeline (r8, +7% rotation VALU).
// ---------------------------------------------------------------------------

__global__ __launch_bounds__(256) void k_agg(const __half* __restrict__ t, __half* __restrict__ out,
                                             const int* __restrict__ rowptr, const int2* __restrict__ csr,
                                             const float* __restrict__ dinv,
                                             float* __restrict__ stats, int N, int nwaves) {
    int tid = threadIdx.x;
    int lane = tid & 63, wid = tid >> 6;
    int grp = lane >> 4;       // edge sub-slot 0..3
    int l16 = lane & 15;       // covers cols [8*l16, 8*l16+8)
    int gw = blockIdx.x * 4 + wid;

    float sx[8] = {0.f, 0.f, 0.f, 0.f, 0.f, 0.f, 0.f, 0.f};
    float qx[8] = {0.f, 0.f, 0.f, 0.f, 0.f, 0.f, 0.f, 0.f};

    int node = gw;
    int e0 = 0, e1 = 0;
    float di = 0.f;
    int2 c[8];
    if (node < N) {
        e0 = rowptr[node]; e1 = rowptr[node + 1]; di = dinv[node];
        int last = e1 - 1;
        #pragma unroll
        for (int j = 0; j < 8; ++j) {
            int idx = e0 + 4 * j + grp;
            int idxc = idx < last ? idx : last;
            if (idxc < 0) idxc = 0;              // deg-0 safety
            c[j] = csr[idxc];
            if (idx >= e1) c[j].y = 0;
        }
    }

    while (node < N) {
        // prefetch next node's metadata
        int nxt = node + nwaves;
        int ep0 = 0, ep1 = 0;
        float dip = 0.f;
        if (nxt < N) { ep0 = rowptr[nxt]; ep1 = rowptr[nxt + 1]; dip = dinv[nxt]; }

        // self row: issue now, consume after the edge loop
        union { half8 h; __half2 h2[4]; } us;
        us.h = *(const half8*)(t + ((size_t)(unsigned)node << 7) + l16 * 8);

        float v[8] = {0.f, 0.f, 0.f, 0.f, 0.f, 0.f, 0.f, 0.f};

        // main volley: addresses/weights already staged in c[]
        #pragma unroll
        for (int j = 0; j < 8; ++j) {
            float wgt = __int_as_float(c[j].y);
            union { half8 h; __half2 h2[4]; } g;
            g.h = *(const half8*)(t + ((size_t)(unsigned)c[j].x << 7) + l16 * 8);
            #pragma unroll
            for (int p = 0; p < 4; ++p) {
                float2 f = __half22float2(g.h2[p]);
                v[2 * p]     = fmaf(wgt, f.x, v[2 * p]);
                v[2 * p + 1] = fmaf(wgt, f.y, v[2 * p + 1]);
            }
        }

        // stage NEXT node's first volley into cn (independent -> compiler may
        // hoist these loads under the gather wait; branch-free)
        int2 cn[8];
        {
            int lastn = ep1 - 1;
            #pragma unroll
            for (int j = 0; j < 8; ++j) {
                int idx = ep0 + 4 * j + grp;
                int idxc = idx < lastn ? idx : lastn;
                if (idxc < 0) idxc = 0;          // deg-0 / past-end safety
                cn[j] = csr[idxc];
                if (idx >= ep1) cn[j].y = 0;
            }
        }

        // rare extra volleys (deg > 32), inline staged (round-3 style)
        for (int e = e0 + 32; e < e1; e += 32) {
            int2 cx[8];
            int last = e1 - 1;
            #pragma unroll
            for (int j = 0; j < 8; ++j) {
                int idx = e + 4 * j + grp;
                int idxc = idx < last ? idx : last;
                cx[j] = csr[idxc];
                if (idx >= e1) cx[j].y = 0;
            }
            #pragma unroll
            for (int j = 0; j < 8; ++j) {
                float wgt = __int_as_float(cx[j].y);
                union { half8 h; __half2 h2[4]; } g;
                g.h = *(const half8*)(t + ((size_t)(unsigned)cx[j].x << 7) + l16 * 8);
                #pragma unroll
                for (int p = 0; p < 4; ++p) {
                    float2 f = __half22float2(g.h2[p]);
                    v[2 * p]     = fmaf(wgt, f.x, v[2 * p]);
                    v[2 * p + 1] = fmaf(wgt, f.y, v[2 * p + 1]);
                }
            }
        }

        // self-loop term — ONLY group 0 (groups are summed by the reduction)
        float sn = (grp == 0) ? di * di : 0.f;
        #pragma unroll
        for (int p = 0; p < 4; ++p) {
            float2 f = __half22float2(us.h2[p]);
            v[2 * p]     = fmaf(sn, f.x, v[2 * p]);
            v[2 * p + 1] = fmaf(sn, f.y, v[2 * p + 1]);
        }

        // combine the 4 group partials
        #pragma unroll
        for (int i = 0; i < 8; ++i) {
            v[i] += __shfl_down(v[i], 32, 64);
            v[i] += __shfl_down(v[i], 16, 64);
        }
        if (grp == 0) {
            union { _Float16 h[8]; uint4 u4; } pk;
            #pragma unroll
            for (int i = 0; i < 8; ++i) {
                v[i] = v[i] > 0.f ? v[i] : LEAKY_S * v[i];
                sx[i] += v[i];
                qx[i] += v[i] * v[i];
                pk.h[i] = (_Float16)v[i];
            }
            *(uint4*)(out + ((size_t)(unsigned)node << 7) + l16 * 8) = pk.u4;
        }

        #pragma unroll
        for (int j = 0; j < 8; ++j) c[j] = cn[j];
        node = nxt; e0 = ep0; e1 = ep1; di = dip;
    }

    __shared__ float red[4 * 128];
    if (grp == 0) {
        *(float4*)(red + wid * 128 + l16 * 8)     = make_float4(sx[0], sx[1], sx[2], sx[3]);
        *(float4*)(red + wid * 128 + l16 * 8 + 4) = make_float4(sx[4], sx[5], sx[6], sx[7]);
    }
    __syncthreads();
    if (tid < 128) {
        float s = red[tid] + red[128 + tid] + red[256 + tid] + red[384 + tid];
        atomicAdd(&stats[tid], s);
    }
    __syncthreads();
    if (grp == 0) {
        *(float4*)(red + wid * 128 + l16 * 8)     = make_float4(qx[0], qx[1], qx[2], qx[3]);
        *(float4*)(red + wid * 128 + l16 * 8 + 4) = make_float4(qx[4], qx[5], qx[6], qx[7]);
    }
    __syncthreads();
    if (tid < 128) {
        float s = red[tid] + red[128 + tid] + red[256 + tid] + red[384 + tid];
        atomicAdd(&stats[128 + tid], s);
    }
}

// ---------------------------------------------------------------------------
// Pooling (h fp16, pool accum fp32). poolfin self-computes graph counts
// (fused former k_cnt_bs) + applies the final BN affine.
// ---------------------------------------------------------------------------

__global__ __launch_bounds__(128) void k_pool(const __half* __restrict__ h, const int* __restrict__ batch,
                                              float* __restrict__ pool, int N, int G) {
    const int CHUNK = 128;
    int start = blockIdx.x * CHUNK;
    if (start >= N) return;
    int end = min(start + CHUNK, N);
    int tid = threadIdx.x;
    float acc = 0.f;
    int cur = batch[start];
    for (int n = start; n < end; ++n) {
        int g = batch[n];
        if (g != cur) {
            if ((unsigned)cur < (unsigned)G) atomicAdd(&pool[(size_t)cur * DIMM + tid], acc);
            acc = 0.f; cur = g;
        }
        acc += __half2float(h[(size_t)n * DIMM + tid]);
    }
    if ((unsigned)cur < (unsigned)G) atomicAdd(&pool[(size_t)cur * DIMM + tid], acc);
}

__global__ __launch_bounds__(256) void k_poolfin(const float* __restrict__ pool, const int* __restrict__ batch,
                                                 const float* __restrict__ stats, const float* __restrict__ gamma,
                                                 const float* __restrict__ beta,
                                                 float* __restrict__ out, int N, int G, float inv_n) {
    int idx = blockIdx.x * 256 + threadIdx.x;
    if (idx < G * DIMM) {
        int g = idx >> 7, c = idx & 127;
        // count nodes of graph g by binary search (batch is sorted)
        int lo = 0, hi = N;
        while (lo < hi) { int mid = (lo + hi) >> 1; if (batch[mid] < g) lo = mid + 1; else hi = mid; }
        int lb = lo;
        lo = 0; hi = N;
        while (lo < hi) { int mid = (lo + hi) >> 1; if (batch[mid] <= g) lo = mid + 1; else hi = mid; }
        int cnt = lo - lb;
        float mu  = stats[c] * inv_n;
        float var = stats[128 + c] * inv_n - mu * mu;
        float a = gamma[c] * rsqrtf(var + EPS_BN);
        float b = beta[c] - mu * a;
        float m = pool[idx] / (float)max(cnt, 1);
        out[idx] = a * m + b;
    }
}

// ---------------------------------------------------------------------------

extern "C" void kernel_launch(void* const* d_in, const int* in_sizes, int n_in,
                              void* d_out, int out_size, void* d_ws, size_t ws_size,
                              hipStream_t stream) {
    const float* x      = (const float*)d_in[0];
    const int*   ei     = (const int*)d_in[1];
    const int*   batch  = (const int*)d_in[2];
    const float* Ws     = (const float*)d_in[3];
    const float* bs     = (const float*)d_in[4];
    const float* gammas = (const float*)d_in[5];
    const float* betas  = (const float*)d_in[6];
    float* outp = (float*)d_out;

    int N = in_sizes[2];
    int E = in_sizes[1] / 2;
    int L = in_sizes[3] / (DIMM * DIMM);
    int G = out_size / DIMM;

    const int* srcv = ei;
    const int* dstv = ei + E;

    int nb = (N + 1023) / 1024;

    char* w = (char*)d_ws;
    auto alloc = [&](size_t bytes) { char* p = w; w += (bytes + 511) & ~size_t(511); return p; };
    size_t pN = ((size_t)N * 4 + 511) & ~size_t(511);
    int*    deg    = (int*)   alloc((size_t)N * 4);
    int*    cursor = (int*)   alloc((size_t)N * 4);   // adjacent to deg: one memset covers both
    int*    rowptr = (int*)   alloc((size_t)(N + 1) * 4);
    int*    bsum   = (int*)   alloc((size_t)nb * 4);
    int*    bofs   = (int*)   alloc((size_t)nb * 4);
    int2*   csr    = (int2*)  alloc((size_t)E * 8);
    float*  dinv   = (float*) alloc((size_t)N * 4);
    __half* hA     = (__half*)alloc((size_t)N * DIMM * 2);
    __half* hB     = (__half*)alloc((size_t)N * DIMM * 2);
    __half* Wt     = (__half*)alloc((size_t)DIMM * DIMM * 2);   // per-layer, rebuilt by k_wbn
    float*  bias2  = (float*) alloc((size_t)DIMM * 4);
    float*  stats  = (float*) alloc((size_t)L * 256 * 4);
    float*  pool   = (float*) alloc((size_t)G * DIMM * 4);

    hipMemsetAsync(deg,   0, pN * 2, stream);                    // deg + cursor
    hipMemsetAsync(stats, 0, (size_t)L * 256 * 4, stream);
    hipMemsetAsync(pool,  0, (size_t)G * DIMM * 4, stream);

    float inv_n = 1.0f / (float)N;

    k_deg  <<<(E + 255) / 256, 256, 0, stream>>>(dstv, deg, E, N);
    k_scanA<<<nb, 256, 0, stream>>>(deg, bsum, dinv, N);         // + dinv (fused)
    k_scanB<<<1, 64, 0, stream>>>(bsum, bofs, rowptr, nb, N);
    k_scanC<<<nb, 1024, 0, stream>>>(deg, bofs, rowptr, N);
    k_fill <<<(E + 255) / 256, 256, 0, stream>>>(srcv, dstv, rowptr, cursor, dinv, csr, E, N);

    const void* cur_in = (const void*)x;
    int a_half = 0;
    for (int l = 0; l < L; ++l) {
        // fold BN affine of layer l-1 into W_l / bias_l
        const float* st = (l > 0) ? stats + (size_t)(l - 1) * 256 : stats;
        const float* gm = (l > 0) ? gammas + (size_t)(l - 1) * DIMM : gammas;
        const float* bt = (l > 0) ? betas + (size_t)(l - 1) * DIMM : betas;
        k_wbn<<<DIMM, DIMM, 0, stream>>>(Ws + (size_t)l * DIMM * DIMM, bs + (size_t)l * DIMM,
                                         st, gm, bt, Wt, bias2, (l == 0) ? 1 : 0, inv_n);
        k_gemm<<<(N + 127) / 128, 256, 0, stream>>>(cur_in, Wt, bias2, hA, N, a_half);
        const int nblk = 2048;   // 8192 waves, strided node assignment
        k_agg<<<nblk, 256, 0, stream>>>(hA, hB, rowptr, csr, dinv,
                                        stats + (size_t)l * 256, N, nblk * 4);
        cur_in = (const void*)hB;
        a_half = 1;
    }

    k_pool<<<(N + 127) / 128, 128, 0, stream>>>(hB, batch, pool, N, G);
    k_poolfin<<<(G * DIMM + 255) / 256, 256, 0, stream>>>(pool, batch, stats + (size_t)(L - 1) * 256,
                                                          gammas + (size_t)(L - 1) * DIMM,
                                                          betas + (size_t)(L - 1) * DIMM, outp, N, G, inv_n);
}